// Round 8
// baseline (112.587 us; speedup 1.0000x reference)
//
#include <hip/hip_runtime.h>

#define B 2
#define L 2048
#define C 256
#define H 8
#define D 32
#define HB 16                         // H*B
#define SCALE 0.17677669529663687f    // 1/sqrt(32)
#define LOG2E 1.4426950408889634f
#define QS (SCALE * LOG2E)

using bf16x8 = __attribute__((ext_vector_type(8))) __bf16;
using f32x4  = __attribute__((ext_vector_type(4))) float;

// round-to-nearest-even f32 -> bf16 bits
static __device__ inline unsigned short f2bf(float f) {
    unsigned u = __float_as_uint(f);
    return (unsigned short)((u + 0x7fffu + ((u >> 16) & 1u)) >> 16);
}
// two f32 -> packed bf16x2 (lo in low half)
static __device__ inline unsigned pk2(float lo, float hi) {
    return (unsigned)f2bf(lo) | ((unsigned)f2bf(hi) << 16);
}

// raw v_exp_f32 (2^x). Q is pre-scaled by SCALE*log2e, so scores are already
// in the log2 domain and one transcendental gives e^(orig score).
static __device__ inline float fexp2(float x) {
#if __has_builtin(__builtin_amdgcn_exp2f)
    return __builtin_amdgcn_exp2f(x);
#else
    float r; asm("v_exp_f32 %0, %1" : "=v"(r) : "v"(x)); return r;
#endif
}

// ---------------------------------------------------------------------------
// Kernel 1: prep. Grid 576 blocks (verified round-5 version, unchanged):
//   blocks 0..511 : V gate in fp32
//   blocks 512..575: Wq/Wk -> FRAGMENT-READY bf16 layout (one contiguous 2 KB
//     burst per wave in qk_gemm); WqT pre-scaled by SCALE*LOG2E.
// ---------------------------------------------------------------------------
__global__ __launch_bounds__(256) void prep_kernel(
    const float* __restrict__ x,   // (B,L,C)
    const float* __restrict__ Wq,  // (C, H*D)
    const float* __restrict__ Wk,
    const float* __restrict__ Wv,  // (C, H)
    unsigned short* __restrict__ WqT,  // 65536 bf16, fragment layout
    unsigned short* __restrict__ WkT,
    float* __restrict__ Vo)            // (HB, L)
{
    __shared__ float smem[256 * 8 + 4 * 8 * 8];
    const int t = threadIdx.x;

    if (blockIdx.x < 512) {
        // ---------------- V gate ----------------
        float (*xrT)[8] = (float(*)[8])smem;           // [256][8]
        float* vred = smem + 256 * 8;                  // [4][8][8]
        const int row0 = blockIdx.x * 8;
        const int b = row0 >> 11;
#pragma unroll
        for (int i = 0; i < 8; ++i)
            xrT[t][i] = x[(row0 + i) * C + t];
        __syncthreads();
        {
            const int cc = t >> 6, sub = t & 63, vi = sub >> 3, vh = sub & 7;
            float va = 0.f;
            for (int c = cc * 64; c < cc * 64 + 64; ++c)
                va += xrT[c][vi] * Wv[c * H + vh];
            vred[(cc * 8 + vi) * 8 + vh] = va;
        }
        __syncthreads();
        if (t < 64) {
            const int i2 = t >> 3, h2 = t & 7;
            const float v = vred[(0 * 8 + i2) * 8 + h2] + vred[(1 * 8 + i2) * 8 + h2] +
                            vred[(2 * 8 + i2) * 8 + h2] + vred[(3 * 8 + i2) * 8 + h2];
            const int l = (row0 + i2) & (L - 1);
            Vo[(h2 * B + b) * L + l] = v;
        }
    } else {
        // ---------------- weight -> fragment-ready bf16 ----------------
        const int bb = blockIdx.x - 512;       // 0..63
        const int mat = bb >> 5;               // 0: Wq, 1: Wk
        const int fid = (bb & 31) * 256 + t;   // 0..8191
        const int col = fid & 15;
        const int quad = (fid >> 4) & 3;
        const int kk = (fid >> 6) & 7;
        const int nt = fid >> 9;               // 0..15
        const int n = nt * 16 + col;
        const int c0 = kk * 32 + quad * 8;
        const float* W = mat ? Wk : Wq;
        unsigned short* WT = mat ? WkT : WqT;
        const float s = mat ? 1.0f : QS;

        float v[8];
#pragma unroll
        for (int j = 0; j < 8; ++j)
            v[j] = W[(c0 + j) * (H * D) + n] * s;
        uint4 u;
        u.x = pk2(v[0], v[1]); u.y = pk2(v[2], v[3]);
        u.z = pk2(v[4], v[5]); u.w = pk2(v[6], v[7]);
        *(uint4*)(WT + (size_t)fid * 8) = u;
    }
}

// ---------------------------------------------------------------------------
// Kernel 2: Q/K projection as bf16 MFMA GEMM.
// (byte-identical to the verified round-5 / 102 us version)
// ---------------------------------------------------------------------------
__global__ __launch_bounds__(256) void qk_gemm_kernel(
    const float* __restrict__ x, const float* __restrict__ pe,
    const unsigned short* __restrict__ WqT, const unsigned short* __restrict__ WkT,
    const float* __restrict__ bq, const float* __restrict__ bk,
    unsigned short* __restrict__ Qo, unsigned short* __restrict__ Ko)
{
    __shared__ uint4 xqs[16][32];   // 16 rows x 32 16B-chunks (8 KB), swizzled
    const int t = threadIdx.x;
    const int w = t >> 6, lane = t & 63;
    const int quad = lane >> 4, col = lane & 15;
    const int row0 = (blockIdx.x >> 2) * 16;
    const int quarter = blockIdx.x & 3;

    // ---- stage x+pe tile as bf16 (coalesced global, swizzled LDS) ----
    {
        const int srow = t >> 4, sc = (t & 15) * 16;   // 16 f32 per thread
        const int grow = row0 + srow;
        const int gl = grow & (L - 1);
        const float* xp = x + (size_t)grow * C + sc;
        const float* pp = pe + (size_t)gl * C + sc;
        const float4 a0 = ((const float4*)xp)[0], a1 = ((const float4*)xp)[1];
        const float4 a2 = ((const float4*)xp)[2], a3 = ((const float4*)xp)[3];
        const float4 p0 = ((const float4*)pp)[0], p1 = ((const float4*)pp)[1];
        const float4 p2 = ((const float4*)pp)[2], p3 = ((const float4*)pp)[3];
        uint4 u0, u1;
        u0.x = pk2(a0.x + p0.x, a0.y + p0.y);
        u0.y = pk2(a0.z + p0.z, a0.w + p0.w);
        u0.z = pk2(a1.x + p1.x, a1.y + p1.y);
        u0.w = pk2(a1.z + p1.z, a1.w + p1.w);
        u1.x = pk2(a2.x + p2.x, a2.y + p2.y);
        u1.y = pk2(a2.z + p2.z, a2.w + p2.w);
        u1.z = pk2(a3.x + p3.x, a3.y + p3.y);
        u1.w = pk2(a3.z + p3.z, a3.w + p3.w);
        const int cb = (t & 15) * 2;
        xqs[srow][(cb + 0) ^ (srow & 7)] = u0;
        xqs[srow][(cb + 1) ^ (srow & 7)] = u1;
    }
    __syncthreads();

    // ---- A-fragments from LDS (swizzled read -> conflict-free) ----
    bf16x8 af[8];
#pragma unroll
    for (int kk = 0; kk < 8; ++kk)
        af[kk] = *(const bf16x8*)&xqs[col][(kk * 4 + quad) ^ (col & 7)];

    // ---- MFMA main: 8 k-steps x {Q,K}; B-frags are contiguous bursts ----
    const int nt = quarter * 4 + w;
    const unsigned short* wq = WqT + (size_t)nt * 8 * 512;
    const unsigned short* wk = WkT + (size_t)nt * 8 * 512;
    const int foff = (quad * 16 + col) * 8;
    f32x4 accq = {0.f, 0.f, 0.f, 0.f};
    f32x4 acck = {0.f, 0.f, 0.f, 0.f};
#pragma unroll
    for (int kk = 0; kk < 8; ++kk) {
        const bf16x8 bq8 = *(const bf16x8*)(wq + kk * 512 + foff);
        const bf16x8 bk8 = *(const bf16x8*)(wk + kk * 512 + foff);
        accq = __builtin_amdgcn_mfma_f32_16x16x32_bf16(af[kk], bq8, accq, 0, 0, 0);
        acck = __builtin_amdgcn_mfma_f32_16x16x32_bf16(af[kk], bk8, acck, 0, 0, 0);
    }

    // ---- epilogue: D[m][n] col=lane&15 -> n, row=quad*4+r -> m ----
    const int n = nt * 16 + col;
    const int h = n >> 5, d = n & 31;
    const float bqv = bq[n] * QS;
    const float bkv = bk[n];
#pragma unroll
    for (int r = 0; r < 4; ++r) {
        const int m = quad * 4 + r;
        const int grow = row0 + m, b = grow >> 11, l = grow & (L - 1);
        const size_t o = ((size_t)(h * B + b) * L + l) * D + d;
        Qo[o] = f2bf(accq[r] + bqv);
        Ko[o] = f2bf(acck[r] + bkv);
    }
}

// ---------------------------------------------------------------------------
// Kernel 3 (pass A): l_q = sum_k 2^(s_qk) over ALL k; G[q] = V[q] / l_q.
// (byte-identical to the verified round-5 / 102 us version)
// ---------------------------------------------------------------------------
__global__ __launch_bounds__(256) void passA_kernel(
    const __bf16* __restrict__ Qb, const __bf16* __restrict__ Kb,
    const float* __restrict__ V, float* __restrict__ G)
{
    __shared__ float lredA[4][4][4][16];  // [wave][quad][reg r][col]
    __shared__ float lredB[4][4][4][16];
    const int tid = threadIdx.x;
    const int w = tid >> 6, lane = tid & 63;
    const int quad = lane >> 4, col = lane & 15;
    const int xcd = blockIdx.x & 7, g = blockIdx.x >> 3;   // g: 0..127
    const int hb = xcd * 2 + (g >> 6), p = g & 63;         // p: tile pair
    const __bf16* Qp = Qb + (size_t)hb * L * D;
    const __bf16* Kp = Kb + (size_t)hb * L * D;

    const bf16x8 qfa = *(const bf16x8*)(Qp + ((2 * p) * 16 + col) * D + quad * 8);
    const bf16x8 qfb = *(const bf16x8*)(Qp + ((2 * p + 1) * 16 + col) * D + quad * 8);
    const f32x4 zero = {0.f, 0.f, 0.f, 0.f};

    float la0 = 0.f, la1 = 0.f, la2 = 0.f, la3 = 0.f;
    float lb0 = 0.f, lb1 = 0.f, lb2 = 0.f, lb3 = 0.f;
    const __bf16* kp = Kp + (w * 512 + col) * D + quad * 8;  // 512 keys/wave
#pragma unroll 4
    for (int kt = 0; kt < 32; ++kt) {
        const bf16x8 kf = *(const bf16x8*)kp;
        kp += 16 * D;
        f32x4 a = __builtin_amdgcn_mfma_f32_16x16x32_bf16(qfa, kf, zero, 0, 0, 0);
        f32x4 bb = __builtin_amdgcn_mfma_f32_16x16x32_bf16(qfb, kf, zero, 0, 0, 0);
        la0 += fexp2(a[0]);  lb0 += fexp2(bb[0]);
        la1 += fexp2(a[1]);  lb1 += fexp2(bb[1]);
        la2 += fexp2(a[2]);  lb2 += fexp2(bb[2]);
        la3 += fexp2(a[3]);  lb3 += fexp2(bb[3]);
    }
    lredA[w][quad][0][col] = la0;  lredB[w][quad][0][col] = lb0;
    lredA[w][quad][1][col] = la1;  lredB[w][quad][1][col] = lb1;
    lredA[w][quad][2][col] = la2;  lredB[w][quad][2][col] = lb2;
    lredA[w][quad][3][col] = la3;  lredB[w][quad][3][col] = lb3;
    __syncthreads();
    if (tid < 32) {                 // tid<16: tile A row tid; else tile B
        const int r8 = tid & 15;    // q row within tile = quad*4 + r
        const int qd = r8 >> 2, r = r8 & 3;
        const float* base = (tid < 16) ? &lredA[0][0][0][0] : &lredB[0][0][0][0];
        float s = 0.f;
#pragma unroll
        for (int w2 = 0; w2 < 4; ++w2) {
            const float* pp = base + ((w2 * 4 + qd) * 4 + r) * 16;
#pragma unroll
            for (int c2 = 0; c2 < 16; ++c2) s += pp[c2];
        }
        const int qt = 2 * p + (tid >> 4);
        const int qq = hb * L + qt * 16 + r8;
        G[qq] = V[qq] / s;
    }
}

// ---------------------------------------------------------------------------
// Kernel 4 (pass B): S[k] = sum_{q >= k} G[q] * 2^(s_qk), fused W=3 pool and
// (B,L,H) output write. Main MFMA loop byte-identical to round-5. NEW:
//  (a) load-balance remap p = praw<32 ? praw : 95-praw (bijective; pairs
//      heavy p with light 63-p on the same CU; proven correct in round 7).
//  (b) fence-free pool fusion: each block REDUNDANTLY computes the two
//      boundary columns S[32p-1], S[32p+32] via a scalar dot path (no
//      cross-block communication, no tickets/fences -- the round-4/6 mistake),
//      then pools its own 32 k values and writes out directly. pool_kernel
//      and the S global array are eliminated.
// ---------------------------------------------------------------------------
__global__ __launch_bounds__(256) void passB_kernel(
    const __bf16* __restrict__ Qb, const __bf16* __restrict__ Kb,
    const float* __restrict__ G, float* __restrict__ out)
{
    __shared__ float sred[2][4][4][16];  // [tile][wave][quad][col]
    __shared__ float bred[2][4];         // boundary partials per wave
    __shared__ float spool[34];          // S[k0-1], S[k0..k0+31], S[k0+32]
    const int tid = threadIdx.x;
    const int w = tid >> 6, lane = tid & 63;
    const int quad = lane >> 4, col = lane & 15;
    const int xcd = blockIdx.x & 7, g = blockIdx.x >> 3;
    const int hb = xcd * 2 + (g >> 6);
    const int praw = g & 63;
    const int p = (praw < 32) ? praw : 95 - praw;   // balance remap
    const int kb0 = 2 * p, kb1 = 2 * p + 1;
    const __bf16* Qp = Qb + (size_t)hb * L * D;
    const __bf16* Kp = Kb + (size_t)hb * L * D;
    const float* Gp = G + hb * L;

    const bf16x8 kf0 = *(const bf16x8*)(Kp + (kb0 * 16 + col) * D + quad * 8);
    const bf16x8 kf1 = *(const bf16x8*)(Kp + (kb1 * 16 + col) * D + quad * 8);
    const f32x4 zero = {0.f, 0.f, 0.f, 0.f};
    const int kidx0 = kb0 * 16 + col;
    const int kidx1 = kb1 * 16 + col;

    float s0 = 0.f, s1 = 0.f;
    int qt = kb0 + w;
    // ---- peeled first q-tile per wave (the only ones touching a diagonal)
    if (qt < 128) {
        const bf16x8 qf = *(const bf16x8*)(Qp + (qt * 16 + col) * D + quad * 8);
        const float4 gg = *(const float4*)(Gp + qt * 16 + quad * 4);
        const int qbase = qt * 16 + quad * 4;
        f32x4 a0 = __builtin_amdgcn_mfma_f32_16x16x32_bf16(qf, kf0, zero, 0, 0, 0);
        if (w == 0) {  // qt == kb0: mask vs kidx0; kb1 contributions all masked
            s0 += (qbase + 0 >= kidx0) ? fexp2(a0[0]) * gg.x : 0.f;
            s0 += (qbase + 1 >= kidx0) ? fexp2(a0[1]) * gg.y : 0.f;
            s0 += (qbase + 2 >= kidx0) ? fexp2(a0[2]) * gg.z : 0.f;
            s0 += (qbase + 3 >= kidx0) ? fexp2(a0[3]) * gg.w : 0.f;
        } else {
            s0 += fexp2(a0[0]) * gg.x + fexp2(a0[1]) * gg.y +
                  fexp2(a0[2]) * gg.z + fexp2(a0[3]) * gg.w;
            f32x4 a1 = __builtin_amdgcn_mfma_f32_16x16x32_bf16(qf, kf1, zero, 0, 0, 0);
            if (w == 1) {  // qt == kb1: mask vs kidx1
                s1 += (qbase + 0 >= kidx1) ? fexp2(a1[0]) * gg.x : 0.f;
                s1 += (qbase + 1 >= kidx1) ? fexp2(a1[1]) * gg.y : 0.f;
                s1 += (qbase + 2 >= kidx1) ? fexp2(a1[2]) * gg.z : 0.f;
                s1 += (qbase + 3 >= kidx1) ? fexp2(a1[3]) * gg.w : 0.f;
            } else {
                s1 += fexp2(a1[0]) * gg.x + fexp2(a1[1]) * gg.y +
                      fexp2(a1[2]) * gg.z + fexp2(a1[3]) * gg.w;
            }
        }
        qt += 4;
    }
    // ---- interior q-tiles: strictly below the diagonal, unmasked
    for (; qt < 128; qt += 4) {
        const bf16x8 qf = *(const bf16x8*)(Qp + (qt * 16 + col) * D + quad * 8);
        const float4 gg = *(const float4*)(Gp + qt * 16 + quad * 4);
        f32x4 a0 = __builtin_amdgcn_mfma_f32_16x16x32_bf16(qf, kf0, zero, 0, 0, 0);
        f32x4 a1 = __builtin_amdgcn_mfma_f32_16x16x32_bf16(qf, kf1, zero, 0, 0, 0);
        s0 += fexp2(a0[0]) * gg.x + fexp2(a0[1]) * gg.y +
              fexp2(a0[2]) * gg.z + fexp2(a0[3]) * gg.w;
        s1 += fexp2(a1[0]) * gg.x + fexp2(a1[1]) * gg.y +
              fexp2(a1[2]) * gg.z + fexp2(a1[3]) * gg.w;
    }
    sred[0][w][quad][col] = s0;
    sred[1][w][quad][col] = s1;

    // ---- redundant boundary columns S[k0-1], S[k0+32] (scalar path) ----
    const int k0 = 32 * p;
    float bl = 0.f, br = 0.f;
    if (p > 0) {
        const int kL = k0 - 1;
        const __bf16* kr = Kp + (size_t)kL * D;
        for (int q = kL + tid; q < L; q += 256) {   // coalesced rows / G
            const __bf16* qr = Qp + (size_t)q * D;
            float s = 0.f;
#pragma unroll
            for (int d = 0; d < D; ++d) s += (float)qr[d] * (float)kr[d];
            bl += fexp2(s) * Gp[q];
        }
    }
    if (p < 63) {
        const int kR = k0 + 32;
        const __bf16* kr = Kp + (size_t)kR * D;
        for (int q = kR + tid; q < L; q += 256) {
            const __bf16* qr = Qp + (size_t)q * D;
            float s = 0.f;
#pragma unroll
            for (int d = 0; d < D; ++d) s += (float)qr[d] * (float)kr[d];
            br += fexp2(s) * Gp[q];
        }
    }
#pragma unroll
    for (int off = 1; off < 64; off <<= 1) {
        bl += __shfl_xor(bl, off);
        br += __shfl_xor(br, off);
    }
    if (lane == 0) { bred[0][w] = bl; bred[1][w] = br; }
    __syncthreads();

    if (tid < 32) {                       // local k = which*16 + c = tid
        const int c = tid & 15, which = tid >> 4;
        float s = 0.f;
#pragma unroll
        for (int j = 0; j < 16; ++j) s += sred[which][j >> 2][j & 3][c];
        spool[1 + tid] = s;
    } else if (tid == 32) {
        spool[0] = bred[0][0] + bred[0][1] + bred[0][2] + bred[0][3];
    } else if (tid == 33) {
        spool[33] = bred[1][0] + bred[1][1] + bred[1][2] + bred[1][3];
    }
    __syncthreads();

    // ---- W=3 SAME pool (pad-excluded counts) + (B,L,H) write ----
    if (tid < 32) {
        const int k = k0 + tid;
        const int h2 = hb >> 1, b2 = hb & 1;    // hb = h*B + b
        float s = spool[1 + tid];
        float n = 1.f;
        if (k > 0)     { s += spool[tid];     n += 1.f; }
        if (k < L - 1) { s += spool[2 + tid]; n += 1.f; }
        out[((size_t)b2 * L + k) * H + h2] = s / n;
    }
}

// ---------------------------------------------------------------------------
extern "C" void kernel_launch(void* const* d_in, const int* in_sizes, int n_in,
                              void* d_out, int out_size, void* d_ws, size_t ws_size,
                              hipStream_t stream)
{
    const float* x  = (const float*)d_in[0];
    const float* Wq = (const float*)d_in[1];
    const float* bq = (const float*)d_in[2];
    const float* Wk = (const float*)d_in[3];
    const float* bk = (const float*)d_in[4];
    const float* Wv = (const float*)d_in[5];
    const float* pe = (const float*)d_in[6];
    float* out = (float*)d_out;

    unsigned short* Qbf = (unsigned short*)d_ws;          // 2 MB
    unsigned short* Kbf = Qbf + (size_t)HB * L * D;       // 2 MB
    float* Vo = (float*)(Kbf + (size_t)HB * L * D);       // 128 KB
    float* G  = Vo + (size_t)HB * L;                      // 128 KB
    unsigned short* WqT = (unsigned short*)(G + (size_t)HB * L);  // 128 KB
    unsigned short* WkT = WqT + (size_t)C * H * D;                // 128 KB

    prep_kernel<<<576, 256, 0, stream>>>(x, Wq, Wk, Wv, WqT, WkT, Vo);
    qk_gemm_kernel<<<1024, 256, 0, stream>>>(x, pe, WqT, WkT, bq, bk, Qbf, Kbf);
    passA_kernel<<<1024, 256, 0, stream>>>(
        (const __bf16*)Qbf, (const __bf16*)Kbf, Vo, G);
    passB_kernel<<<1024, 256, 0, stream>>>(
        (const __bf16*)Qbf, (const __bf16*)Kbf, G, out);
}

// Round 9
// 101.848 us; speedup vs baseline: 1.1054x; 1.1054x over previous
//
#include <hip/hip_runtime.h>

#define B 2
#define L 2048
#define C 256
#define H 8
#define D 32
#define HB 16                         // H*B
#define SCALE 0.17677669529663687f    // 1/sqrt(32)
#define LOG2E 1.4426950408889634f
#define QS (SCALE * LOG2E)

using bf16x8 = __attribute__((ext_vector_type(8))) __bf16;
using f32x4  = __attribute__((ext_vector_type(4))) float;

// round-to-nearest-even f32 -> bf16 bits
static __device__ inline unsigned short f2bf(float f) {
    unsigned u = __float_as_uint(f);
    return (unsigned short)((u + 0x7fffu + ((u >> 16) & 1u)) >> 16);
}
// two f32 -> packed bf16x2 (lo in low half)
static __device__ inline unsigned pk2(float lo, float hi) {
    return (unsigned)f2bf(lo) | ((unsigned)f2bf(hi) << 16);
}

// raw v_exp_f32 (2^x). Q is pre-scaled by SCALE*log2e, so scores are already
// in the log2 domain and one transcendental gives e^(orig score).
static __device__ inline float fexp2(float x) {
#if __has_builtin(__builtin_amdgcn_exp2f)
    return __builtin_amdgcn_exp2f(x);
#else
    float r; asm("v_exp_f32 %0, %1" : "=v"(r) : "v"(x)); return r;
#endif
}

// ---------------------------------------------------------------------------
// Kernel 1: prep. Grid 576 blocks (verified round-5 version, unchanged):
//   blocks 0..511 : V gate in fp32
//   blocks 512..575: Wq/Wk -> FRAGMENT-READY bf16 layout (one contiguous 2 KB
//     burst per wave in qk_gemm); WqT pre-scaled by SCALE*LOG2E.
// ---------------------------------------------------------------------------
__global__ __launch_bounds__(256) void prep_kernel(
    const float* __restrict__ x,   // (B,L,C)
    const float* __restrict__ Wq,  // (C, H*D)
    const float* __restrict__ Wk,
    const float* __restrict__ Wv,  // (C, H)
    unsigned short* __restrict__ WqT,  // 65536 bf16, fragment layout
    unsigned short* __restrict__ WkT,
    float* __restrict__ Vo)            // (HB, L)
{
    __shared__ float smem[256 * 8 + 4 * 8 * 8];
    const int t = threadIdx.x;

    if (blockIdx.x < 512) {
        // ---------------- V gate ----------------
        float (*xrT)[8] = (float(*)[8])smem;           // [256][8]
        float* vred = smem + 256 * 8;                  // [4][8][8]
        const int row0 = blockIdx.x * 8;
        const int b = row0 >> 11;
#pragma unroll
        for (int i = 0; i < 8; ++i)
            xrT[t][i] = x[(row0 + i) * C + t];
        __syncthreads();
        {
            const int cc = t >> 6, sub = t & 63, vi = sub >> 3, vh = sub & 7;
            float va = 0.f;
            for (int c = cc * 64; c < cc * 64 + 64; ++c)
                va += xrT[c][vi] * Wv[c * H + vh];
            vred[(cc * 8 + vi) * 8 + vh] = va;
        }
        __syncthreads();
        if (t < 64) {
            const int i2 = t >> 3, h2 = t & 7;
            const float v = vred[(0 * 8 + i2) * 8 + h2] + vred[(1 * 8 + i2) * 8 + h2] +
                            vred[(2 * 8 + i2) * 8 + h2] + vred[(3 * 8 + i2) * 8 + h2];
            const int l = (row0 + i2) & (L - 1);
            Vo[(h2 * B + b) * L + l] = v;
        }
    } else {
        // ---------------- weight -> fragment-ready bf16 ----------------
        const int bb = blockIdx.x - 512;       // 0..63
        const int mat = bb >> 5;               // 0: Wq, 1: Wk
        const int fid = (bb & 31) * 256 + t;   // 0..8191
        const int col = fid & 15;
        const int quad = (fid >> 4) & 3;
        const int kk = (fid >> 6) & 7;
        const int nt = fid >> 9;               // 0..15
        const int n = nt * 16 + col;
        const int c0 = kk * 32 + quad * 8;
        const float* W = mat ? Wk : Wq;
        unsigned short* WT = mat ? WkT : WqT;
        const float s = mat ? 1.0f : QS;

        float v[8];
#pragma unroll
        for (int j = 0; j < 8; ++j)
            v[j] = W[(c0 + j) * (H * D) + n] * s;
        uint4 u;
        u.x = pk2(v[0], v[1]); u.y = pk2(v[2], v[3]);
        u.z = pk2(v[4], v[5]); u.w = pk2(v[6], v[7]);
        *(uint4*)(WT + (size_t)fid * 8) = u;
    }
}

// ---------------------------------------------------------------------------
// Kernel 2: Q/K projection as bf16 MFMA GEMM.
// (byte-identical to the verified round-5 / 102 us version)
// ---------------------------------------------------------------------------
__global__ __launch_bounds__(256) void qk_gemm_kernel(
    const float* __restrict__ x, const float* __restrict__ pe,
    const unsigned short* __restrict__ WqT, const unsigned short* __restrict__ WkT,
    const float* __restrict__ bq, const float* __restrict__ bk,
    unsigned short* __restrict__ Qo, unsigned short* __restrict__ Ko)
{
    __shared__ uint4 xqs[16][32];   // 16 rows x 32 16B-chunks (8 KB), swizzled
    const int t = threadIdx.x;
    const int w = t >> 6, lane = t & 63;
    const int quad = lane >> 4, col = lane & 15;
    const int row0 = (blockIdx.x >> 2) * 16;
    const int quarter = blockIdx.x & 3;

    // ---- stage x+pe tile as bf16 (coalesced global, swizzled LDS) ----
    {
        const int srow = t >> 4, sc = (t & 15) * 16;   // 16 f32 per thread
        const int grow = row0 + srow;
        const int gl = grow & (L - 1);
        const float* xp = x + (size_t)grow * C + sc;
        const float* pp = pe + (size_t)gl * C + sc;
        const float4 a0 = ((const float4*)xp)[0], a1 = ((const float4*)xp)[1];
        const float4 a2 = ((const float4*)xp)[2], a3 = ((const float4*)xp)[3];
        const float4 p0 = ((const float4*)pp)[0], p1 = ((const float4*)pp)[1];
        const float4 p2 = ((const float4*)pp)[2], p3 = ((const float4*)pp)[3];
        uint4 u0, u1;
        u0.x = pk2(a0.x + p0.x, a0.y + p0.y);
        u0.y = pk2(a0.z + p0.z, a0.w + p0.w);
        u0.z = pk2(a1.x + p1.x, a1.y + p1.y);
        u0.w = pk2(a1.z + p1.z, a1.w + p1.w);
        u1.x = pk2(a2.x + p2.x, a2.y + p2.y);
        u1.y = pk2(a2.z + p2.z, a2.w + p2.w);
        u1.z = pk2(a3.x + p3.x, a3.y + p3.y);
        u1.w = pk2(a3.z + p3.z, a3.w + p3.w);
        const int cb = (t & 15) * 2;
        xqs[srow][(cb + 0) ^ (srow & 7)] = u0;
        xqs[srow][(cb + 1) ^ (srow & 7)] = u1;
    }
    __syncthreads();

    // ---- A-fragments from LDS (swizzled read -> conflict-free) ----
    bf16x8 af[8];
#pragma unroll
    for (int kk = 0; kk < 8; ++kk)
        af[kk] = *(const bf16x8*)&xqs[col][(kk * 4 + quad) ^ (col & 7)];

    // ---- MFMA main: 8 k-steps x {Q,K}; B-frags are contiguous bursts ----
    const int nt = quarter * 4 + w;
    const unsigned short* wq = WqT + (size_t)nt * 8 * 512;
    const unsigned short* wk = WkT + (size_t)nt * 8 * 512;
    const int foff = (quad * 16 + col) * 8;
    f32x4 accq = {0.f, 0.f, 0.f, 0.f};
    f32x4 acck = {0.f, 0.f, 0.f, 0.f};
#pragma unroll
    for (int kk = 0; kk < 8; ++kk) {
        const bf16x8 bq8 = *(const bf16x8*)(wq + kk * 512 + foff);
        const bf16x8 bk8 = *(const bf16x8*)(wk + kk * 512 + foff);
        accq = __builtin_amdgcn_mfma_f32_16x16x32_bf16(af[kk], bq8, accq, 0, 0, 0);
        acck = __builtin_amdgcn_mfma_f32_16x16x32_bf16(af[kk], bk8, acck, 0, 0, 0);
    }

    // ---- epilogue: D[m][n] col=lane&15 -> n, row=quad*4+r -> m ----
    const int n = nt * 16 + col;
    const int h = n >> 5, d = n & 31;
    const float bqv = bq[n] * QS;
    const float bkv = bk[n];
#pragma unroll
    for (int r = 0; r < 4; ++r) {
        const int m = quad * 4 + r;
        const int grow = row0 + m, b = grow >> 11, l = grow & (L - 1);
        const size_t o = ((size_t)(h * B + b) * L + l) * D + d;
        Qo[o] = f2bf(accq[r] + bqv);
        Ko[o] = f2bf(acck[r] + bkv);
    }
}

// ---------------------------------------------------------------------------
// Kernel 3 (pass A): l_q = sum_k 2^(s_qk) over ALL k; G[q] = V[q] / l_q.
// Identical arithmetic to round-5; ONLY change: unroll 4 -> 8 on the k-loop
// (kf addresses are load-independent, so depth-8 keeps 8 L2 loads in flight
// instead of 4; +16 VGPR, no spill at this kernel's footprint).
// ---------------------------------------------------------------------------
__global__ __launch_bounds__(256) void passA_kernel(
    const __bf16* __restrict__ Qb, const __bf16* __restrict__ Kb,
    const float* __restrict__ V, float* __restrict__ G)
{
    __shared__ float lredA[4][4][4][16];  // [wave][quad][reg r][col]
    __shared__ float lredB[4][4][4][16];
    const int tid = threadIdx.x;
    const int w = tid >> 6, lane = tid & 63;
    const int quad = lane >> 4, col = lane & 15;
    const int xcd = blockIdx.x & 7, g = blockIdx.x >> 3;   // g: 0..127
    const int hb = xcd * 2 + (g >> 6), p = g & 63;         // p: tile pair
    const __bf16* Qp = Qb + (size_t)hb * L * D;
    const __bf16* Kp = Kb + (size_t)hb * L * D;

    const bf16x8 qfa = *(const bf16x8*)(Qp + ((2 * p) * 16 + col) * D + quad * 8);
    const bf16x8 qfb = *(const bf16x8*)(Qp + ((2 * p + 1) * 16 + col) * D + quad * 8);
    const f32x4 zero = {0.f, 0.f, 0.f, 0.f};

    float la0 = 0.f, la1 = 0.f, la2 = 0.f, la3 = 0.f;
    float lb0 = 0.f, lb1 = 0.f, lb2 = 0.f, lb3 = 0.f;
    const __bf16* kp = Kp + (w * 512 + col) * D + quad * 8;  // 512 keys/wave
#pragma unroll 8
    for (int kt = 0; kt < 32; ++kt) {
        const bf16x8 kf = *(const bf16x8*)kp;
        kp += 16 * D;
        f32x4 a = __builtin_amdgcn_mfma_f32_16x16x32_bf16(qfa, kf, zero, 0, 0, 0);
        f32x4 bb = __builtin_amdgcn_mfma_f32_16x16x32_bf16(qfb, kf, zero, 0, 0, 0);
        la0 += fexp2(a[0]);  lb0 += fexp2(bb[0]);
        la1 += fexp2(a[1]);  lb1 += fexp2(bb[1]);
        la2 += fexp2(a[2]);  lb2 += fexp2(bb[2]);
        la3 += fexp2(a[3]);  lb3 += fexp2(bb[3]);
    }
    lredA[w][quad][0][col] = la0;  lredB[w][quad][0][col] = lb0;
    lredA[w][quad][1][col] = la1;  lredB[w][quad][1][col] = lb1;
    lredA[w][quad][2][col] = la2;  lredB[w][quad][2][col] = lb2;
    lredA[w][quad][3][col] = la3;  lredB[w][quad][3][col] = lb3;
    __syncthreads();
    if (tid < 32) {                 // tid<16: tile A row tid; else tile B
        const int r8 = tid & 15;    // q row within tile = quad*4 + r
        const int qd = r8 >> 2, r = r8 & 3;
        const float* base = (tid < 16) ? &lredA[0][0][0][0] : &lredB[0][0][0][0];
        float s = 0.f;
#pragma unroll
        for (int w2 = 0; w2 < 4; ++w2) {
            const float* pp = base + ((w2 * 4 + qd) * 4 + r) * 16;
#pragma unroll
            for (int c2 = 0; c2 < 16; ++c2) s += pp[c2];
        }
        const int qt = 2 * p + (tid >> 4);
        const int qq = hb * L + qt * 16 + r8;
        G[qq] = V[qq] / s;
    }
}

// ---------------------------------------------------------------------------
// Kernel 4 (pass B): S[k] = sum_{q >= k} G[q] * 2^(s_qk).
// Identical to round-5 EXCEPT the load-balance remap (proven bit-identical in
// rounds 7/8): p = praw<32 ? praw : 95-praw pairs heavy p with light 63-p on
// the same CU (worst-CU work 192 -> 130 wave-iter units).
// ---------------------------------------------------------------------------
__global__ __launch_bounds__(256) void passB_kernel(
    const __bf16* __restrict__ Qb, const __bf16* __restrict__ Kb,
    const float* __restrict__ G, float* __restrict__ S)
{
    __shared__ float sred[2][4][4][16];  // [tile][wave][quad][col]
    const int tid = threadIdx.x;
    const int w = tid >> 6, lane = tid & 63;
    const int quad = lane >> 4, col = lane & 15;
    const int xcd = blockIdx.x & 7, g = blockIdx.x >> 3;
    const int hb = xcd * 2 + (g >> 6);
    const int praw = g & 63;
    const int p = (praw < 32) ? praw : 95 - praw;   // balance remap
    const int kb0 = 2 * p, kb1 = 2 * p + 1;
    const __bf16* Qp = Qb + (size_t)hb * L * D;
    const __bf16* Kp = Kb + (size_t)hb * L * D;
    const float* Gp = G + hb * L;

    const bf16x8 kf0 = *(const bf16x8*)(Kp + (kb0 * 16 + col) * D + quad * 8);
    const bf16x8 kf1 = *(const bf16x8*)(Kp + (kb1 * 16 + col) * D + quad * 8);
    const f32x4 zero = {0.f, 0.f, 0.f, 0.f};
    const int kidx0 = kb0 * 16 + col;
    const int kidx1 = kb1 * 16 + col;

    float s0 = 0.f, s1 = 0.f;
    int qt = kb0 + w;
    // ---- peeled first q-tile per wave (the only ones touching a diagonal)
    if (qt < 128) {
        const bf16x8 qf = *(const bf16x8*)(Qp + (qt * 16 + col) * D + quad * 8);
        const float4 gg = *(const float4*)(Gp + qt * 16 + quad * 4);
        const int qbase = qt * 16 + quad * 4;
        f32x4 a0 = __builtin_amdgcn_mfma_f32_16x16x32_bf16(qf, kf0, zero, 0, 0, 0);
        if (w == 0) {  // qt == kb0: mask vs kidx0; kb1 contributions all masked
            s0 += (qbase + 0 >= kidx0) ? fexp2(a0[0]) * gg.x : 0.f;
            s0 += (qbase + 1 >= kidx0) ? fexp2(a0[1]) * gg.y : 0.f;
            s0 += (qbase + 2 >= kidx0) ? fexp2(a0[2]) * gg.z : 0.f;
            s0 += (qbase + 3 >= kidx0) ? fexp2(a0[3]) * gg.w : 0.f;
        } else {
            s0 += fexp2(a0[0]) * gg.x + fexp2(a0[1]) * gg.y +
                  fexp2(a0[2]) * gg.z + fexp2(a0[3]) * gg.w;
            f32x4 a1 = __builtin_amdgcn_mfma_f32_16x16x32_bf16(qf, kf1, zero, 0, 0, 0);
            if (w == 1) {  // qt == kb1: mask vs kidx1
                s1 += (qbase + 0 >= kidx1) ? fexp2(a1[0]) * gg.x : 0.f;
                s1 += (qbase + 1 >= kidx1) ? fexp2(a1[1]) * gg.y : 0.f;
                s1 += (qbase + 2 >= kidx1) ? fexp2(a1[2]) * gg.z : 0.f;
                s1 += (qbase + 3 >= kidx1) ? fexp2(a1[3]) * gg.w : 0.f;
            } else {
                s1 += fexp2(a1[0]) * gg.x + fexp2(a1[1]) * gg.y +
                      fexp2(a1[2]) * gg.z + fexp2(a1[3]) * gg.w;
            }
        }
        qt += 4;
    }
    // ---- interior q-tiles: strictly below the diagonal, unmasked
    for (; qt < 128; qt += 4) {
        const bf16x8 qf = *(const bf16x8*)(Qp + (qt * 16 + col) * D + quad * 8);
        const float4 gg = *(const float4*)(Gp + qt * 16 + quad * 4);
        f32x4 a0 = __builtin_amdgcn_mfma_f32_16x16x32_bf16(qf, kf0, zero, 0, 0, 0);
        f32x4 a1 = __builtin_amdgcn_mfma_f32_16x16x32_bf16(qf, kf1, zero, 0, 0, 0);
        s0 += fexp2(a0[0]) * gg.x + fexp2(a0[1]) * gg.y +
              fexp2(a0[2]) * gg.z + fexp2(a0[3]) * gg.w;
        s1 += fexp2(a1[0]) * gg.x + fexp2(a1[1]) * gg.y +
              fexp2(a1[2]) * gg.z + fexp2(a1[3]) * gg.w;
    }
    sred[0][w][quad][col] = s0;
    sred[1][w][quad][col] = s1;
    __syncthreads();
    if (tid < 32) {
        const int c = tid & 15, which = tid >> 4;
        float s = 0.f;
#pragma unroll
        for (int j = 0; j < 16; ++j) s += sred[which][j >> 2][j & 3][c];
        S[hb * L + (2 * p + which) * 16 + c] = s;
    }
}

// ---------------------------------------------------------------------------
// Kernel 5: windowed average along k (W=3, SAME, pad-excluded counts) and
// layout transform to (B, L, H).  (verified round-5 version)
// ---------------------------------------------------------------------------
__global__ __launch_bounds__(256) void pool_kernel(
    const float* __restrict__ S, float* __restrict__ out)
{
    const int flat = blockIdx.x * 256 + threadIdx.x;  // (b*L + k)*H + h
    const int h = flat & 7;
    const int k = (flat >> 3) & (L - 1);
    const int b = flat >> 14;
    const float* Sb = S + (h * B + b) * L;
    float s = Sb[k];
    float cnt = 1.f;
    if (k > 0)     { s += Sb[k - 1]; cnt += 1.f; }
    if (k < L - 1) { s += Sb[k + 1]; cnt += 1.f; }
    out[flat] = s / cnt;
}

// ---------------------------------------------------------------------------
extern "C" void kernel_launch(void* const* d_in, const int* in_sizes, int n_in,
                              void* d_out, int out_size, void* d_ws, size_t ws_size,
                              hipStream_t stream)
{
    const float* x  = (const float*)d_in[0];
    const float* Wq = (const float*)d_in[1];
    const float* bq = (const float*)d_in[2];
    const float* Wk = (const float*)d_in[3];
    const float* bk = (const float*)d_in[4];
    const float* Wv = (const float*)d_in[5];
    const float* pe = (const float*)d_in[6];
    float* out = (float*)d_out;

    unsigned short* Qbf = (unsigned short*)d_ws;          // 2 MB
    unsigned short* Kbf = Qbf + (size_t)HB * L * D;       // 2 MB
    float* Vo = (float*)(Kbf + (size_t)HB * L * D);       // 128 KB
    float* G  = Vo + (size_t)HB * L;                      // 128 KB
    float* S  = G  + (size_t)HB * L;                      // 128 KB
    unsigned short* WqT = (unsigned short*)(S + (size_t)HB * L);  // 128 KB
    unsigned short* WkT = WqT + (size_t)C * H * D;                // 128 KB

    prep_kernel<<<576, 256, 0, stream>>>(x, Wq, Wk, Wv, WqT, WkT, Vo);
    qk_gemm_kernel<<<1024, 256, 0, stream>>>(x, pe, WqT, WkT, bq, bk, Qbf, Kbf);
    passA_kernel<<<1024, 256, 0, stream>>>(
        (const __bf16*)Qbf, (const __bf16*)Kbf, Vo, G);
    passB_kernel<<<1024, 256, 0, stream>>>(
        (const __bf16*)Qbf, (const __bf16*)Kbf, G, S);
    pool_kernel<<<(B * L * H) / 256, 256, 0, stream>>>(S, out);
}